// Round 7
// baseline (206.537 us; speedup 1.0000x reference)
//
#include <hip/hip_runtime.h>
#include <stdint.h>

#define HW 16384
#define NI 64
#define NM 256
#define WORDS 256

// plane-strip padding: stride 136 floats/row (4 guard cols each side, zeroed)
#define PR 136
// 16-row tile + 10-row halo each side = 36-row window (10 sweeps, no exchange)
#define TROWS 16
#define WROWS 36
#define NTHREADS 576          // 18 row-pairs x 32 quads
#define NBLK 512              // 64 img x 8 tiles
// state padding: stride 34 words/row (1 guard word each side, zeroed)
#define SR 34
// strip: planes k=0,1,2 of EVEN window rows only (19 rows alloc: 18 used + pad)
#define SPR 19
#define SPSZ (SPR * PR)       // 2584 floats per strip plane

// ws layout
#define OFF_PACKED (2u << 20)    // 512 KB bit-packed masks [word][mask]
#define OFF_DIOUT  0x280000u     // 256 KB diou transposed diouT[col][row]
#define OFF_COMPM  0x2C0000u
#define OFF_CNT    0x2C1000u     // 512 per-block partial counts (8 per image)

// ---------------------------------------------------------------------------
// Build one window row's kernel-weight fragments into REGISTERS
// (R13-proven sequence, verbatim math; out[k] = res[0..3] of plane k).
// ---------------------------------------------------------------------------
__device__ __forceinline__ void build_row(
    const float* __restrict__ fb, const int y, const int xc, const bool inimg,
    float4 (&out)[4]) {
    #pragma clang fp contract(off)
    float c0[4], c1[4], c2[4];
    if (inimg) {
        const int pp = y * 128 + xc;
        float4 cv0 = *(const float4*)&fb[pp];
        float4 cv1 = *(const float4*)&fb[HW + pp];
        float4 cv2 = *(const float4*)&fb[2 * HW + pp];
        c0[0]=cv0.x+10.0f; c0[1]=cv0.y+10.0f; c0[2]=cv0.z+10.0f; c0[3]=cv0.w+10.0f;
        c1[0]=cv1.x+10.0f; c1[1]=cv1.y+10.0f; c1[2]=cv1.z+10.0f; c1[3]=cv1.w+10.0f;
        c2[0]=cv2.x+10.0f; c2[1]=cv2.y+10.0f; c2[2]=cv2.z+10.0f; c2[3]=cv2.w+10.0f;
    }
    #pragma unroll
    for (int k = 0; k < 4; ++k) {
        const int dy = (k < 3) ? -1 : 0;
        const int dx = (k < 3) ? (k - 1) : -1;
        float res[4] = {0.0f, 0.0f, 0.0f, 0.0f};
        if (inimg) {
            const int ny = y + dy;
            if ((unsigned)ny < 128u) {
                #pragma unroll
                for (int j = 0; j < 4; ++j) {
                    const int nx = xc + j + dx;
                    if ((unsigned)nx < 128u) {
                        const int qq = ny * 128 + nx;
                        float u0 = fb[qq] + 10.0f;
                        float u1 = fb[HW + qq] + 10.0f;
                        float u2 = fb[2 * HW + qq] + 10.0f;
                        float d0 = u0 - c0[j], d1 = u1 - c1[j], d2 = u2 - c2[j];
                        float ss = d0 * d0;
                        ss = ss + d1 * d1;
                        ss = ss + d2 * d2;
                        float color = (-ss) / 0.5f;
                        float sp = (float)(dy * dy + dx * dx) / 1800.0f;
                        res[j] = 3.0f * expf(color - sp);
                    }
                }
            }
        }
        out[k] = make_float4(res[0], res[1], res[2], res[3]);
    }
}

// ---------------------------------------------------------------------------
// Iter-0 state for one window row (proven). stw0 fully written (0 for OOB),
// stw1 zeroed at OOB slots, guard words of both buffers zeroed.
// ---------------------------------------------------------------------------
__device__ __forceinline__ void stage_init_row(
    const float* __restrict__ x, const float* __restrict__ targets,
    uint32_t* __restrict__ stw0, uint32_t* __restrict__ stw1, const int img,
    const int y, const int wrow, const int q, const int xc, const bool inimg) {
    #pragma clang fp contract(off)
    uint32_t st = 0;
    if (inimg) {
        const size_t gp = (size_t)img * HW + y * 128 + xc;
        const float4 xv = *(const float4*)(x + gp);
        const float4 tv = *(const float4*)(targets + gp);
        float xs[4] = {xv.x, xv.y, xv.z, xv.w};
        float ts[4] = {tv.x, tv.y, tv.z, tv.w};
        #pragma unroll
        for (int j = 0; j < 4; ++j) {
            float xt = xs[j] * ts[j];
            int b1 = (xt > 0.5f) ? 1 : 0;
            int tb = (ts[j] > 0.5f) ? 1 : 0;
            st |= (uint32_t)(b1 | ((b1 ^ 1) << 1) | (tb << 2)) << (8 * j);
        }
    }
    stw0[wrow * SR + 1 + q] = st;
    if (!inimg) stw1[wrow * SR + 1 + q] = 0;
    if (q == 0)  { stw0[wrow * SR + 0]  = 0; stw1[wrow * SR + 0]  = 0; }
    if (q == 31) { stw0[wrow * SR + 33] = 0; stw1[wrow * SR + 33] = 0; }
}

// ---------------------------------------------------------------------------
// CRF cell core (R13-proven math, verbatim): 9 state words + 9x4 kernel
// weights -> output word. Pure deterministic map; no LDS access.
// ---------------------------------------------------------------------------
__device__ __forceinline__ uint32_t crf_core(const float (&kw)[9][4],
                                             const uint32_t (&in9)[9]) {
    #pragma clang fp contract(off)
    const float l45 = 0.7985076962177716f;  // -log(0.45f)
    const float l55 = 0.5978370007556204f;  // -log(0.55f)
    const uint32_t wcen = in9[4];
    float lx1r[3][6], lx0r[3][6];
    #pragma unroll
    for (int r = 0; r < 3; ++r) {
        const uint32_t wm = in9[r * 3 + 0];
        const uint32_t wc = in9[r * 3 + 1];
        const uint32_t wp = in9[r * 3 + 2];
        unsigned char b[6];
        b[0] = wm >> 24;
        b[1] = wc & 0xff; b[2] = (wc >> 8) & 0xff;
        b[3] = (wc >> 16) & 0xff; b[4] = wc >> 24;
        b[5] = wp & 0xff;
        #pragma unroll
        for (int m = 0; m < 6; ++m) {
            lx1r[r][m] = (b[m] & 1) ? l55 : l45;
            lx0r[r][m] = (b[m] & 2) ? l55 : l45;
        }
    }
    float a0[4] = {0.f, 0.f, 0.f, 0.f}, a1[4] = {0.f, 0.f, 0.f, 0.f};
    #pragma unroll
    for (int k = 0; k < 9; ++k) {
        const int r = k / 3, m0 = k % 3;
        #pragma unroll
        for (int j = 0; j < 4; ++j) {
            const float kwv = kw[k][j];
            const float t1 = lx1r[r][j + m0] * kwv;  // mul then add
            const float t0 = lx0r[r][j + m0] * kwv;
            a1[j] = a1[j] + t1;
            a0[j] = a0[j] + t0;
        }
    }
    // epilogue (proven exact sequence)
    uint32_t ow = 0;
    #pragma unroll
    for (int j = 0; j < 4; ++j) {
        const unsigned char sc = (wcen >> (8 * j)) & 0xffu;
        const float tval = (sc & 4) ? 1.0f : 0.0f;
        const float e1 = expf(-a1[j]);
        const float e0 = expf(-a0[j]);
        const float m1 = e1 * tval;
        const float f1 = m1 + 1e-6f;
        const float f0 = e0 + 1e-6f;
        const float den = f0 + f1;
        const float r1 = f1 / den;
        const float r0v = f0 / den;
        const int s1 = (r1 > 0.5f) ? 1 : 0;
        const int s0 = (r0v > 0.5f) ? 1 : 0;
        ow |= (uint32_t)(s1 | (s0 << 1) | (sc & 4)) << (8 * j);
    }
    return ow;
}

// ---------------------------------------------------------------------------
// Single-pass CRF, occupancy-oriented: 512 blocks (64 img x 8 tiles of 16
// rows), 576 threads, 2 adjacent window rows/thread, 36-row window. Sweep s
// computes rows [max(0,r0-9+s), min(128,r0+25-s)) — own rows exact after 10
// sweeps, zero inter-block exchange (same shrinking-halo proof, R4/R5-
// validated). LDS holds ONLY: k=0,1,2 plane strips of EVEN window rows
// (row-C operands for cell B on memo-miss) + 2 state buffers + chg ->
// 40.8 KB static -> 2-3 blocks/CU co-resident, 18 waves/CU (was 127 KB ->
// 1 block -> 13 waves). All other kw operands in registers; lane-neighbor
// scalars via __shfl of the same values the old code re-read from LDS
// (edge lanes -> 0.0 == the zeroed guard columns, bit-exact).
// NOTE: stw buffer selection uses ternaries, NOT a pointer array — a
// static-initialized array of LDS pointers hits an unsupported
// addrspacecast static initializer on gfx950 (R6 compile failure).
// ---------------------------------------------------------------------------
__global__ __launch_bounds__(576, 4) void crf10_kernel(
    const float* __restrict__ feat, const float* __restrict__ seg,
    unsigned long long* __restrict__ packed, const float* __restrict__ x,
    const float* __restrict__ targets, float* __restrict__ out,
    int* __restrict__ counters) {
    #pragma clang fp contract(off)
    __shared__ float strip[3 * SPSZ];        // 31008 B
    __shared__ uint32_t stw0[WROWS * SR];    // 4896 B
    __shared__ uint32_t stw1[WROWS * SR];    // 4896 B
    __shared__ int chg[10];                  // total 40840 B

    const int tid = threadIdx.x, bid = blockIdx.x;
    const int img = bid >> 3;                // 8 tiles per image
    const int r0 = (bid & 7) * TROWS;
    const int relp = tid >> 5;               // 0..17
    const int q = tid & 31;
    const int xc = q * 4;
    const int wrowA = 2 * relp, wrowB = wrowA + 1;
    const int yA = r0 - 10 + wrowA, yB = yA + 1;
    const bool inA = (unsigned)yA < 128u, inB = (unsigned)yB < 128u;
    const int sbaseA = wrowA * SR + 1 + q, sbaseB = wrowB * SR + 1 + q;
    const float* fb = feat + (size_t)img * 3 * HW;

    // ---- pack, balanced over all 4608 waves (proven ballot body) -----------
    {
        const int wave = tid >> 6, lane = tid & 63;
        const int gw = bid * 9 + wave;           // 0..4607
        for (int gwi = gw; gwi < 65536; gwi += 4608) {
            const int i = gwi >> 8, w = gwi & 255;
            float v = seg[(size_t)i * HW + w * 64 + lane];
            unsigned long long m = __ballot(v > 0.5f);
            if (lane == 0) packed[w * NM + i] = m;
        }
    }

    // ---- build both rows into registers; spill only even-row k0..2 strip ---
    float4 ap[4], bp[4];
    build_row(fb, yA, xc, inA, ap);
    build_row(fb, yB, xc, inB, bp);
    #pragma unroll
    for (int k = 0; k < 3; ++k) {
        *(float4*)&strip[k * SPSZ + relp * PR + 4 + xc] = ap[k];
        if (q == 0)
            *(float4*)&strip[k * SPSZ + relp * PR + 0] = make_float4(0, 0, 0, 0);
        if (q == 31)
            *(float4*)&strip[k * SPSZ + relp * PR + 132] = make_float4(0, 0, 0, 0);
    }
    stage_init_row(x, targets, stw0, stw1, img, yA, wrowA, q, xc, inA);
    stage_init_row(x, targets, stw0, stw1, img, yB, wrowB, q, xc, inB);
    if (tid < 10) chg[tid] = 0;

    // lane-neighbor scalars (== old LDS guard-column reads, bit-exact)
    float a_s5 = __shfl_down(ap[3].x, 1); if (q == 31) a_s5 = 0.0f;
    float b_s5 = __shfl_down(bp[3].x, 1); if (q == 31) b_s5 = 0.0f;
    float b_s6 = __shfl_up(bp[2].w, 1);   if (q == 0)  b_s6 = 0.0f;
    float b_s8 = __shfl_down(bp[0].x, 1); if (q == 31) b_s8 = 0.0f;
    __syncthreads();

    const float kwA[9][4] = {
        {ap[0].x, ap[0].y, ap[0].z, ap[0].w},
        {ap[1].x, ap[1].y, ap[1].z, ap[1].w},
        {ap[2].x, ap[2].y, ap[2].z, ap[2].w},
        {ap[3].x, ap[3].y, ap[3].z, ap[3].w},
        {3.0f, 3.0f, 3.0f, 3.0f},
        {ap[3].y, ap[3].z, ap[3].w, a_s5},
        {b_s6, bp[2].x, bp[2].y, bp[2].z},
        {bp[1].x, bp[1].y, bp[1].z, bp[1].w},
        {bp[0].y, bp[0].z, bp[0].w, b_s8}};

    // ---- 10 sweeps: 1 barrier each, warm memo, block early-exit ------------
    uint32_t pinA[9], pinB[9];
    uint32_t powvA = 0, powvB = 0;
    bool hpA = false, hpB = false;
    int cur = 0;
    for (int s = 0; s < 10; ++s) {
        const int lo = (r0 - 9 + s < 0) ? 0 : r0 - 9 + s;
        const int hi = (r0 + 25 - s > 128) ? 128 : r0 + 25 - s;
        const bool actA = (yA >= lo) && (yA < hi);
        const bool actB = (yB >= lo) && (yB < hi);
        const uint32_t* sw = cur ? stw1 : stw0;
        uint32_t* swn = cur ? stw0 : stw1;
        bool changed = false;
        if (actA || actB) {
            // shared middle rows (A,B) of both cells' 3x3 neighborhoods
            const uint32_t ra0 = sw[sbaseA - 1], ra1 = sw[sbaseA], ra2 = sw[sbaseA + 1];
            const uint32_t rb0 = sw[sbaseB - 1], rb1 = sw[sbaseB], rb2 = sw[sbaseB + 1];
            if (actA) {
                const uint32_t in9[9] = {sw[sbaseA - SR - 1], sw[sbaseA - SR],
                                         sw[sbaseA - SR + 1], ra0, ra1, ra2,
                                         rb0, rb1, rb2};
                bool same = hpA;
                #pragma unroll
                for (int m = 0; m < 9; ++m) same = same && (in9[m] == pinA[m]);
                uint32_t ow;
                if (same) {
                    ow = powvA;  // deterministic map on identical inputs — exact
                } else {
                    ow = crf_core(kwA, in9);
                    #pragma unroll
                    for (int m = 0; m < 9; ++m) pinA[m] = in9[m];
                    powvA = ow;
                    hpA = true;
                }
                swn[sbaseA] = ow;
                changed = (ow != ra1);
            }
            if (actB) {
                const uint32_t in9[9] = {ra0, ra1, ra2, rb0, rb1, rb2,
                                         sw[sbaseB + SR - 1], sw[sbaseB + SR],
                                         sw[sbaseB + SR + 1]};
                bool same = hpB;
                #pragma unroll
                for (int m = 0; m < 9; ++m) same = same && (in9[m] == pinB[m]);
                uint32_t ow;
                if (same) {
                    ow = powvB;
                } else {
                    // row-C fragments from compact strip (sweep-invariant)
                    const int cb = (relp + 1) * PR + 4 + xc;
                    const float4 c_p0 = *(const float4*)&strip[0 * SPSZ + cb];
                    const float4 c_p1 = *(const float4*)&strip[1 * SPSZ + cb];
                    const float4 c_p2 = *(const float4*)&strip[2 * SPSZ + cb];
                    const float  c_s6 = strip[2 * SPSZ + cb - 1];
                    const float  c_s8 = strip[0 * SPSZ + cb + 4];
                    const float kwB[9][4] = {
                        {bp[0].x, bp[0].y, bp[0].z, bp[0].w},
                        {bp[1].x, bp[1].y, bp[1].z, bp[1].w},
                        {bp[2].x, bp[2].y, bp[2].z, bp[2].w},
                        {bp[3].x, bp[3].y, bp[3].z, bp[3].w},
                        {3.0f, 3.0f, 3.0f, 3.0f},
                        {bp[3].y, bp[3].z, bp[3].w, b_s5},
                        {c_s6, c_p2.x, c_p2.y, c_p2.z},
                        {c_p1.x, c_p1.y, c_p1.z, c_p1.w},
                        {c_p0.y, c_p0.z, c_p0.w, c_s8}};
                    ow = crf_core(kwB, in9);
                    #pragma unroll
                    for (int m = 0; m < 9; ++m) pinB[m] = in9[m];
                    powvB = ow;
                    hpB = true;
                }
                swn[sbaseB] = ow;
                changed = changed || (ow != rb1);
            }
        }
        unsigned long long bal = __ballot(changed);
        if ((tid & 63) == 0 && bal) atomicOr(&chg[s], 1);
        __syncthreads();
        if (chg[s] == 0) break;  // fixed point: later sweeps identical (exact)
        cur ^= 1;
    }

    // ---- emission: masks + this block's count ------------------------------
    int cnt = 0;
    {
        const uint32_t* swf = cur ? stw1 : stw0;
        float* om = out + NM + (size_t)img * HW;
        if (yA >= r0 && yA < r0 + TROWS) {
            const uint32_t w = swf[sbaseA];
            *(float4*)(om + yA * 128 + xc) =
                make_float4((float)(w & 1), (float)((w >> 8) & 1),
                            (float)((w >> 16) & 1), (float)((w >> 24) & 1));
            cnt += __popc(w & 0x01010101u);
        }
        if (yB >= r0 && yB < r0 + TROWS) {
            const uint32_t w = swf[sbaseB];
            *(float4*)(om + yB * 128 + xc) =
                make_float4((float)(w & 1), (float)((w >> 8) & 1),
                            (float)((w >> 16) & 1), (float)((w >> 24) & 1));
            cnt += __popc(w & 0x01010101u);
        }
    }
    __syncthreads();   // before strip reuse as cred
    {
        int* cred = (int*)strip;
        cred[tid] = cnt;
        if (tid < 448) cred[576 + tid] = 0;   // pad to 1024
        __syncthreads();
        for (int off = 512; off > 0; off >>= 1) {
            if (tid < off) cred[tid] += cred[tid + off];
            __syncthreads();
        }
        if (tid == 0) counters[bid] = cred[0];  // per-block partial, no atomics
    }
}

// ---------------------------------------------------------------------------
// NMS diou + compm (proven, verbatim).
// ---------------------------------------------------------------------------
__global__ __launch_bounds__(256) void diou_compm_kernel(
    const unsigned long long* __restrict__ packed, const int* __restrict__ labels,
    float* __restrict__ diouT, float* __restrict__ compm) {
    #pragma clang fp contract(off)
    __shared__ unsigned long long colj[WORDS];
    __shared__ float red[NM];
    const int j = blockIdx.x, i = threadIdx.x;
    colj[i] = packed[i * NM + j];
    __syncthreads();
    int inter = 0, si = 0, sj = 0;
    for (int w = 0; w < WORDS; ++w) {
        unsigned long long a = colj[w];
        unsigned long long b = packed[w * NM + i];
        inter += __popcll(a & b);
        sj += __popcll(a);
        si += __popcll(b);
    }
    float d = 0.0f;
    if (j > i && labels[i] == labels[j]) {
        float u = (float)(si + sj - inter);   // exact integers in f32
        d = (float)inter / u;
    }
    diouT[j * NM + i] = d;
    red[i] = d;
    __syncthreads();
    for (int off = 128; off > 0; off >>= 1) {
        if (i < off) red[i] = fmaxf(red[i], red[i + off]);
        __syncthreads();
    }
    if (i == 0) {
        float m = red[0];
        float t = m * m;
        compm[j] = expf(-2.0f * t);
    }
}

// ---------------------------------------------------------------------------
// coef (proven prologue, verbatim) + valid from per-block partial counts.
// ---------------------------------------------------------------------------
__global__ __launch_bounds__(256) void coef_valid_kernel(
    const float* __restrict__ scores, const float* __restrict__ diouT,
    const float* __restrict__ compm, const int* __restrict__ counters,
    float* __restrict__ out) {
    #pragma clang fp contract(off)
    __shared__ float red[NM];
    const int bid = blockIdx.x, tid = threadIdx.x;
    float d = diouT[bid * NM + tid];
    float dd = d * d;
    float dec = expf(-2.0f * dd);
    red[tid] = dec / compm[tid];
    __syncthreads();
    for (int off = 128; off > 0; off >>= 1) {
        if (tid < off) red[tid] = fminf(red[tid], red[tid + off]);
        __syncthreads();
    }
    if (tid == 0) out[bid] = scores[bid] * red[0];
    if (bid == 0 && tid < NI) {
        int c = 0;
        #pragma unroll
        for (int t = 0; t < 8; ++t) c += counters[8 * tid + t];
        // 16384*0.05 = 819.2, 16384*0.95 = 15564.8; counts are integers
        out[NM + (size_t)NI * HW + tid] = (c >= 820 && c <= 15564) ? 1.0f : 0.0f;
    }
}

extern "C" void kernel_launch(void* const* d_in, const int* in_sizes, int n_in,
                              void* d_out, int out_size, void* d_ws, size_t ws_size,
                              hipStream_t stream) {
    const float* seg = (const float*)d_in[0];
    const float* cate_scores = (const float*)d_in[1];
    const float* feat = (const float*)d_in[2];
    const float* x = (const float*)d_in[3];
    const float* targets = (const float*)d_in[4];
    const int* labels = (const int*)d_in[5];
    float* out = (float*)d_out;
    char* ws = (char*)d_ws;

    unsigned long long* packed = (unsigned long long*)(ws + OFF_PACKED);
    float* diouT = (float*)(ws + OFF_DIOUT);
    float* compm = (float*)(ws + OFF_COMPM);
    int* counters = (int*)(ws + OFF_CNT);

    // Node 1: full 10-iter CRF + pack + masks + per-block counts
    crf10_kernel<<<NBLK, NTHREADS, 0, stream>>>(feat, seg, packed, x, targets,
                                                out, counters);
    // Node 2: NMS diou + compm (needs packed)
    diou_compm_kernel<<<NM, 256, 0, stream>>>(packed, labels, diouT, compm);
    // Node 3: coef + valid (needs diouT/compm/counters)
    coef_valid_kernel<<<NM, 256, 0, stream>>>(cate_scores, diouT, compm,
                                              counters, out);
}

// Round 8
// 161.192 us; speedup vs baseline: 1.2813x; 1.2813x over previous
//
#include <hip/hip_runtime.h>
#include <stdint.h>

#define HW 16384
#define NI 64
#define NM 256
#define WORDS 256

// plane-strip padding: stride 136 floats/row (4 guard cols each side, zeroed)
#define PR 136
// 32-row tile + 10-row halo each side = 52-row window (10 sweeps, no exchange)
#define TROWS 32
#define WROWS 52
#define NTHREADS 832          // 26 row-pairs x 32 quads (R5-proven geometry)
#define NBLK 256              // 64 img x 4 tiles
// state padding: stride 34 words/row (1 guard word each side, zeroed)
#define SR 34
// strip: planes k=0,1,2 of EVEN window rows (26 used + 1 pad; row 26 never read)
#define SPR 27
#define SPSZ (SPR * PR)       // 3672 floats per strip plane

// ws layout
#define OFF_PACKED (2u << 20)    // 512 KB bit-packed masks [word][mask]
#define OFF_DIOUT  0x280000u     // 256 KB diou transposed diouT[col][row]
#define OFF_COMPM  0x2C0000u
#define OFF_CNT    0x2C1000u     // 256 per-block partial counts (4 per image)

// ---------------------------------------------------------------------------
// 16-bit -> 64-bit spread (bit i -> bit 4i), for vectorized mask pack.
// ---------------------------------------------------------------------------
__device__ __forceinline__ unsigned long long spread4(unsigned long long t) {
    t &= 0xFFFFull;
    t = (t | (t << 24)) & 0x000000FF000000FFull;
    t = (t | (t << 12)) & 0x000F000F000F000Full;
    t = (t | (t << 6))  & 0x0303030303030303ull;
    t = (t | (t << 3))  & 0x1111111111111111ull;
    return t;
}

// ---------------------------------------------------------------------------
// Load one feat row (3 channels, 4 px) and apply +10 once. Same input bits,
// same single f32 add as the original per-use `fb[qq]+10.0f` -> identical
// values; zeros for OOB rows (consumed only under row-validity guards).
// ---------------------------------------------------------------------------
__device__ __forceinline__ void load_row(const float* __restrict__ fb,
                                         const int y, const int xc,
                                         float (&u)[3][4]) {
    #pragma clang fp contract(off)
    if ((unsigned)y < 128u) {
        const int pp = y * 128 + xc;
        float4 v0 = *(const float4*)&fb[pp];
        float4 v1 = *(const float4*)&fb[HW + pp];
        float4 v2 = *(const float4*)&fb[2 * HW + pp];
        u[0][0]=v0.x+10.0f; u[0][1]=v0.y+10.0f; u[0][2]=v0.z+10.0f; u[0][3]=v0.w+10.0f;
        u[1][0]=v1.x+10.0f; u[1][1]=v1.y+10.0f; u[1][2]=v1.z+10.0f; u[1][3]=v1.w+10.0f;
        u[2][0]=v2.x+10.0f; u[2][1]=v2.y+10.0f; u[2][2]=v2.z+10.0f; u[2][3]=v2.w+10.0f;
    } else {
        #pragma unroll
        for (int c = 0; c < 3; ++c)
            #pragma unroll
            for (int j = 0; j < 4; ++j) u[c][j] = 0.0f;
    }
}

// ---------------------------------------------------------------------------
// One kernel-weight element (R13-proven sequence, verbatim).
// ---------------------------------------------------------------------------
__device__ __forceinline__ float cell_res(float n0, float n1, float n2,
                                          float c0, float c1, float c2,
                                          float sp) {
    #pragma clang fp contract(off)
    float d0 = n0 - c0, d1 = n1 - c1, d2 = n2 - c2;
    float ss = d0 * d0;
    ss = ss + d1 * d1;
    ss = ss + d2 * d2;
    float color = (-ss) / 0.5f;
    return 3.0f * expf(color - sp);
}

// ---------------------------------------------------------------------------
// Build one row's 4 kernel planes from register data + lane shuffles.
// uc = center row (+10), ut = row y-1 (+10), lt/rt = its lane-neighbor
// scalars, lc = center row's left neighbor. Bounds guards identical to the
// proven build (OOB row or col -> exact 0). k: 0..2 dy=-1 dx=k-1; 3 dy=0 dx=-1.
// ---------------------------------------------------------------------------
__device__ __forceinline__ void compute_row(
    const float (&uc)[3][4], const float (&ut)[3][4],
    const float (&lt)[3], const float (&rt)[3], const float (&lc)[3],
    const bool in_y, const bool in_t, const int q, float4 (&out)[4]) {
    #pragma clang fp contract(off)
    const float sp1 = 1.0f / 1800.0f;   // (dy*dy+dx*dx)=1, const-folded as before
    const float sp2 = 2.0f / 1800.0f;   // (dy*dy+dx*dx)=2
    float r[4];
    // k=0: dy=-1, dx=-1
    r[0] = r[1] = r[2] = r[3] = 0.0f;
    if (in_y && in_t) {
        if (q > 0)
            r[0] = cell_res(lt[0], lt[1], lt[2], uc[0][0], uc[1][0], uc[2][0], sp2);
        r[1] = cell_res(ut[0][0], ut[1][0], ut[2][0], uc[0][1], uc[1][1], uc[2][1], sp2);
        r[2] = cell_res(ut[0][1], ut[1][1], ut[2][1], uc[0][2], uc[1][2], uc[2][2], sp2);
        r[3] = cell_res(ut[0][2], ut[1][2], ut[2][2], uc[0][3], uc[1][3], uc[2][3], sp2);
    }
    out[0] = make_float4(r[0], r[1], r[2], r[3]);
    // k=1: dy=-1, dx=0
    r[0] = r[1] = r[2] = r[3] = 0.0f;
    if (in_y && in_t) {
        r[0] = cell_res(ut[0][0], ut[1][0], ut[2][0], uc[0][0], uc[1][0], uc[2][0], sp1);
        r[1] = cell_res(ut[0][1], ut[1][1], ut[2][1], uc[0][1], uc[1][1], uc[2][1], sp1);
        r[2] = cell_res(ut[0][2], ut[1][2], ut[2][2], uc[0][2], uc[1][2], uc[2][2], sp1);
        r[3] = cell_res(ut[0][3], ut[1][3], ut[2][3], uc[0][3], uc[1][3], uc[2][3], sp1);
    }
    out[1] = make_float4(r[0], r[1], r[2], r[3]);
    // k=2: dy=-1, dx=+1
    r[0] = r[1] = r[2] = r[3] = 0.0f;
    if (in_y && in_t) {
        r[0] = cell_res(ut[0][1], ut[1][1], ut[2][1], uc[0][0], uc[1][0], uc[2][0], sp2);
        r[1] = cell_res(ut[0][2], ut[1][2], ut[2][2], uc[0][1], uc[1][1], uc[2][1], sp2);
        r[2] = cell_res(ut[0][3], ut[1][3], ut[2][3], uc[0][2], uc[1][2], uc[2][2], sp2);
        if (q < 31)
            r[3] = cell_res(rt[0], rt[1], rt[2], uc[0][3], uc[1][3], uc[2][3], sp2);
    }
    out[2] = make_float4(r[0], r[1], r[2], r[3]);
    // k=3: dy=0, dx=-1 (neighbor row is the center row itself)
    r[0] = r[1] = r[2] = r[3] = 0.0f;
    if (in_y) {
        if (q > 0)
            r[0] = cell_res(lc[0], lc[1], lc[2], uc[0][0], uc[1][0], uc[2][0], sp1);
        r[1] = cell_res(uc[0][0], uc[1][0], uc[2][0], uc[0][1], uc[1][1], uc[2][1], sp1);
        r[2] = cell_res(uc[0][1], uc[1][1], uc[2][1], uc[0][2], uc[1][2], uc[2][2], sp1);
        r[3] = cell_res(uc[0][2], uc[1][2], uc[2][2], uc[0][3], uc[1][3], uc[2][3], sp1);
    }
    out[3] = make_float4(r[0], r[1], r[2], r[3]);
}

// ---------------------------------------------------------------------------
// Iter-0 state for one window row (proven). stw0 fully written (0 for OOB),
// stw1 zeroed at OOB slots, guard words of both buffers zeroed.
// ---------------------------------------------------------------------------
__device__ __forceinline__ void stage_init_row(
    const float* __restrict__ x, const float* __restrict__ targets,
    uint32_t* __restrict__ stw0, uint32_t* __restrict__ stw1, const int img,
    const int y, const int wrow, const int q, const int xc, const bool inimg) {
    #pragma clang fp contract(off)
    uint32_t st = 0;
    if (inimg) {
        const size_t gp = (size_t)img * HW + y * 128 + xc;
        const float4 xv = *(const float4*)(x + gp);
        const float4 tv = *(const float4*)(targets + gp);
        float xs[4] = {xv.x, xv.y, xv.z, xv.w};
        float ts[4] = {tv.x, tv.y, tv.z, tv.w};
        #pragma unroll
        for (int j = 0; j < 4; ++j) {
            float xt = xs[j] * ts[j];
            int b1 = (xt > 0.5f) ? 1 : 0;
            int tb = (ts[j] > 0.5f) ? 1 : 0;
            st |= (uint32_t)(b1 | ((b1 ^ 1) << 1) | (tb << 2)) << (8 * j);
        }
    }
    stw0[wrow * SR + 1 + q] = st;
    if (!inimg) stw1[wrow * SR + 1 + q] = 0;
    if (q == 0)  { stw0[wrow * SR + 0]  = 0; stw1[wrow * SR + 0]  = 0; }
    if (q == 31) { stw0[wrow * SR + 33] = 0; stw1[wrow * SR + 33] = 0; }
}

// ---------------------------------------------------------------------------
// CRF cell core (R13-proven math, verbatim): 9 state words + 9x4 kernel
// weights -> output word. Pure deterministic map; no LDS access.
// ---------------------------------------------------------------------------
__device__ __forceinline__ uint32_t crf_core(const float (&kw)[9][4],
                                             const uint32_t (&in9)[9]) {
    #pragma clang fp contract(off)
    const float l45 = 0.7985076962177716f;  // -log(0.45f)
    const float l55 = 0.5978370007556204f;  // -log(0.55f)
    const uint32_t wcen = in9[4];
    float lx1r[3][6], lx0r[3][6];
    #pragma unroll
    for (int r = 0; r < 3; ++r) {
        const uint32_t wm = in9[r * 3 + 0];
        const uint32_t wc = in9[r * 3 + 1];
        const uint32_t wp = in9[r * 3 + 2];
        unsigned char b[6];
        b[0] = wm >> 24;
        b[1] = wc & 0xff; b[2] = (wc >> 8) & 0xff;
        b[3] = (wc >> 16) & 0xff; b[4] = wc >> 24;
        b[5] = wp & 0xff;
        #pragma unroll
        for (int m = 0; m < 6; ++m) {
            lx1r[r][m] = (b[m] & 1) ? l55 : l45;
            lx0r[r][m] = (b[m] & 2) ? l55 : l45;
        }
    }
    float a0[4] = {0.f, 0.f, 0.f, 0.f}, a1[4] = {0.f, 0.f, 0.f, 0.f};
    #pragma unroll
    for (int k = 0; k < 9; ++k) {
        const int r = k / 3, m0 = k % 3;
        #pragma unroll
        for (int j = 0; j < 4; ++j) {
            const float kwv = kw[k][j];
            const float t1 = lx1r[r][j + m0] * kwv;  // mul then add
            const float t0 = lx0r[r][j + m0] * kwv;
            a1[j] = a1[j] + t1;
            a0[j] = a0[j] + t0;
        }
    }
    // epilogue (proven exact sequence)
    uint32_t ow = 0;
    #pragma unroll
    for (int j = 0; j < 4; ++j) {
        const unsigned char sc = (wcen >> (8 * j)) & 0xffu;
        const float tval = (sc & 4) ? 1.0f : 0.0f;
        const float e1 = expf(-a1[j]);
        const float e0 = expf(-a0[j]);
        const float m1 = e1 * tval;
        const float f1 = m1 + 1e-6f;
        const float f0 = e0 + 1e-6f;
        const float den = f0 + f1;
        const float r1 = f1 / den;
        const float r0v = f0 / den;
        const int s1 = (r1 > 0.5f) ? 1 : 0;
        const int s0 = (r0v > 0.5f) ? 1 : 0;
        ow |= (uint32_t)(s1 | (s0 << 1) | (sc & 4)) << (8 * j);
    }
    return ow;
}

// ---------------------------------------------------------------------------
// Single-pass CRF, R5 geometry (proven fastest: 256 blocks = 64 img x 4
// tiles of 32 rows, 832 threads, 52-row window, sweeps
// [max(0,r0-9+s), min(128,r0+41-s))), with the R7/R8 front-phase rework:
//  - pack: float4 + 4 ballots + spread4 (4x shorter dependent chain),
//  - build: 9 float4 row loads + __shfl lane neighbors (replaces 72 scalar
//    loads + addr math; identical FP sequence, edge lanes == zero guards),
//  - LDS: only k=0..2 strips of EVEN rows + state buffers (58.2 KB static).
// Occupancy is pinned at 1 block/CU on this runtime (R2/R5/R7 evidence), so
// the win is shorter latency chains + less issue work per block.
// ---------------------------------------------------------------------------
__global__ __launch_bounds__(832, 4) void crf10_kernel(
    const float* __restrict__ feat, const float* __restrict__ seg,
    unsigned long long* __restrict__ packed, const float* __restrict__ x,
    const float* __restrict__ targets, float* __restrict__ out,
    int* __restrict__ counters) {
    #pragma clang fp contract(off)
    __shared__ float strip[3 * SPSZ];        // 44064 B
    __shared__ uint32_t stw0[WROWS * SR];    // 7072 B
    __shared__ uint32_t stw1[WROWS * SR];    // 7072 B
    __shared__ int chg[10];                  // total 58248 B < 64 KiB static

    const int tid = threadIdx.x, bid = blockIdx.x;
    const int img = bid >> 2;                // 4 tiles per image
    const int r0 = (bid & 3) * TROWS;
    const int relp = tid >> 5;               // 0..25
    const int q = tid & 31;
    const int xc = q * 4;
    const int wrowA = 2 * relp, wrowB = wrowA + 1;
    const int yA = r0 - 10 + wrowA, yB = yA + 1;
    const bool inA = (unsigned)yA < 128u, inB = (unsigned)yB < 128u;
    const int sbaseA = wrowA * SR + 1 + q, sbaseB = wrowB * SR + 1 + q;
    const float* fb = feat + (size_t)img * 3 * HW;

    // ---- pack, vectorized: 1 KB/wave-iter, 4 ballots, bit-spread -----------
    // bit b of packed[w*NM+i] = (seg[i*HW + w*64 + b] > 0.5), identical to the
    // proven scalar ballot: lane l holds px 4l+e; word t<4 of the 256-px group
    // collects bit 4(l-16t)+e from ballot_e.
    {
        const int wave = tid >> 6, lane = tid & 63;
        const int gw = bid * 13 + wave;          // 3328 waves, 16384 groups
        for (int gwi = gw; gwi < 16384; gwi += 3328) {
            const int i = gwi >> 6, w4 = gwi & 63;
            const float4 v =
                *(const float4*)&seg[(size_t)i * HW + w4 * 256 + lane * 4];
            unsigned long long b0 = __ballot(v.x > 0.5f);
            unsigned long long b1 = __ballot(v.y > 0.5f);
            unsigned long long b2 = __ballot(v.z > 0.5f);
            unsigned long long b3 = __ballot(v.w > 0.5f);
            if (lane < 4) {
                const int sh = lane * 16;
                unsigned long long word = spread4(b0 >> sh)
                                        | (spread4(b1 >> sh) << 1)
                                        | (spread4(b2 >> sh) << 2)
                                        | (spread4(b3 >> sh) << 3);
                packed[(size_t)(w4 * 4 + lane) * NM + i] = word;
            }
        }
    }

    // ---- build rows A,B from registers + shuffles --------------------------
    float uT[3][4], uA[3][4], uB[3][4];
    load_row(fb, yA - 1, xc, uT);
    load_row(fb, yA, xc, uA);
    float lT[3], rT[3], lA[3], rA[3], lB[3];
    #pragma unroll
    for (int c = 0; c < 3; ++c) {
        lT[c] = __shfl_up(uT[c][3], 1);
        rT[c] = __shfl_down(uT[c][0], 1);
        lA[c] = __shfl_up(uA[c][3], 1);
        rA[c] = __shfl_down(uA[c][0], 1);
    }
    float4 ap[4], bp[4];
    compute_row(uA, uT, lT, rT, lA, inA, (unsigned)(yA - 1) < 128u, q, ap);
    load_row(fb, yB, xc, uB);
    #pragma unroll
    for (int c = 0; c < 3; ++c) lB[c] = __shfl_up(uB[c][3], 1);
    compute_row(uB, uA, lA, rA, lB, inB, inA, q, bp);

    // strip: even-row planes k=0..2 (row-C operands for cell B on memo-miss)
    #pragma unroll
    for (int k = 0; k < 3; ++k) {
        *(float4*)&strip[k * SPSZ + relp * PR + 4 + xc] = ap[k];
        if (q == 0)
            *(float4*)&strip[k * SPSZ + relp * PR + 0] = make_float4(0, 0, 0, 0);
        if (q == 31)
            *(float4*)&strip[k * SPSZ + relp * PR + 132] = make_float4(0, 0, 0, 0);
    }
    stage_init_row(x, targets, stw0, stw1, img, yA, wrowA, q, xc, inA);
    stage_init_row(x, targets, stw0, stw1, img, yB, wrowB, q, xc, inB);
    if (tid < 10) chg[tid] = 0;

    // lane-neighbor kw scalars (edge lanes -> 0.0 == zeroed guard cols)
    float a_s5 = __shfl_down(ap[3].x, 1); if (q == 31) a_s5 = 0.0f;
    float b_s5 = __shfl_down(bp[3].x, 1); if (q == 31) b_s5 = 0.0f;
    float b_s6 = __shfl_up(bp[2].w, 1);   if (q == 0)  b_s6 = 0.0f;
    float b_s8 = __shfl_down(bp[0].x, 1); if (q == 31) b_s8 = 0.0f;
    __syncthreads();

    const float kwA[9][4] = {
        {ap[0].x, ap[0].y, ap[0].z, ap[0].w},
        {ap[1].x, ap[1].y, ap[1].z, ap[1].w},
        {ap[2].x, ap[2].y, ap[2].z, ap[2].w},
        {ap[3].x, ap[3].y, ap[3].z, ap[3].w},
        {3.0f, 3.0f, 3.0f, 3.0f},
        {ap[3].y, ap[3].z, ap[3].w, a_s5},
        {b_s6, bp[2].x, bp[2].y, bp[2].z},
        {bp[1].x, bp[1].y, bp[1].z, bp[1].w},
        {bp[0].y, bp[0].z, bp[0].w, b_s8}};

    // ---- 10 sweeps: 1 barrier each, warm memo, block early-exit ------------
    uint32_t pinA[9], pinB[9];
    uint32_t powvA = 0, powvB = 0;
    bool hpA = false, hpB = false;
    int cur = 0;
    for (int s = 0; s < 10; ++s) {
        const int lo = (r0 - 9 + s < 0) ? 0 : r0 - 9 + s;
        const int hi = (r0 + 41 - s > 128) ? 128 : r0 + 41 - s;
        const bool actA = (yA >= lo) && (yA < hi);
        const bool actB = (yB >= lo) && (yB < hi);
        const uint32_t* sw = cur ? stw1 : stw0;
        uint32_t* swn = cur ? stw0 : stw1;
        bool changed = false;
        if (actA || actB) {
            const uint32_t ra0 = sw[sbaseA - 1], ra1 = sw[sbaseA], ra2 = sw[sbaseA + 1];
            const uint32_t rb0 = sw[sbaseB - 1], rb1 = sw[sbaseB], rb2 = sw[sbaseB + 1];
            if (actA) {
                const uint32_t in9[9] = {sw[sbaseA - SR - 1], sw[sbaseA - SR],
                                         sw[sbaseA - SR + 1], ra0, ra1, ra2,
                                         rb0, rb1, rb2};
                bool same = hpA;
                #pragma unroll
                for (int m = 0; m < 9; ++m) same = same && (in9[m] == pinA[m]);
                uint32_t ow;
                if (same) {
                    ow = powvA;  // deterministic map on identical inputs — exact
                } else {
                    ow = crf_core(kwA, in9);
                    #pragma unroll
                    for (int m = 0; m < 9; ++m) pinA[m] = in9[m];
                    powvA = ow;
                    hpA = true;
                }
                swn[sbaseA] = ow;
                changed = (ow != ra1);
            }
            if (actB) {
                const uint32_t in9[9] = {ra0, ra1, ra2, rb0, rb1, rb2,
                                         sw[sbaseB + SR - 1], sw[sbaseB + SR],
                                         sw[sbaseB + SR + 1]};
                bool same = hpB;
                #pragma unroll
                for (int m = 0; m < 9; ++m) same = same && (in9[m] == pinB[m]);
                uint32_t ow;
                if (same) {
                    ow = powvB;
                } else {
                    // row-C fragments from strip (sweep-invariant; row 26
                    // never read: relp=25's cell B is never active)
                    const int cb = (relp + 1) * PR + 4 + xc;
                    const float4 c_p0 = *(const float4*)&strip[0 * SPSZ + cb];
                    const float4 c_p1 = *(const float4*)&strip[1 * SPSZ + cb];
                    const float4 c_p2 = *(const float4*)&strip[2 * SPSZ + cb];
                    const float  c_s6 = strip[2 * SPSZ + cb - 1];
                    const float  c_s8 = strip[0 * SPSZ + cb + 4];
                    const float kwB[9][4] = {
                        {bp[0].x, bp[0].y, bp[0].z, bp[0].w},
                        {bp[1].x, bp[1].y, bp[1].z, bp[1].w},
                        {bp[2].x, bp[2].y, bp[2].z, bp[2].w},
                        {bp[3].x, bp[3].y, bp[3].z, bp[3].w},
                        {3.0f, 3.0f, 3.0f, 3.0f},
                        {bp[3].y, bp[3].z, bp[3].w, b_s5},
                        {c_s6, c_p2.x, c_p2.y, c_p2.z},
                        {c_p1.x, c_p1.y, c_p1.z, c_p1.w},
                        {c_p0.y, c_p0.z, c_p0.w, c_s8}};
                    ow = crf_core(kwB, in9);
                    #pragma unroll
                    for (int m = 0; m < 9; ++m) pinB[m] = in9[m];
                    powvB = ow;
                    hpB = true;
                }
                swn[sbaseB] = ow;
                changed = changed || (ow != rb1);
            }
        }
        unsigned long long bal = __ballot(changed);
        if ((tid & 63) == 0 && bal) atomicOr(&chg[s], 1);
        __syncthreads();
        if (chg[s] == 0) break;  // fixed point: later sweeps identical (exact)
        cur ^= 1;
    }

    // ---- emission: masks + this block's count ------------------------------
    int cnt = 0;
    {
        const uint32_t* swf = cur ? stw1 : stw0;
        float* om = out + NM + (size_t)img * HW;
        if (yA >= r0 && yA < r0 + TROWS) {
            const uint32_t w = swf[sbaseA];
            *(float4*)(om + yA * 128 + xc) =
                make_float4((float)(w & 1), (float)((w >> 8) & 1),
                            (float)((w >> 16) & 1), (float)((w >> 24) & 1));
            cnt += __popc(w & 0x01010101u);
        }
        if (yB >= r0 && yB < r0 + TROWS) {
            const uint32_t w = swf[sbaseB];
            *(float4*)(om + yB * 128 + xc) =
                make_float4((float)(w & 1), (float)((w >> 8) & 1),
                            (float)((w >> 16) & 1), (float)((w >> 24) & 1));
            cnt += __popc(w & 0x01010101u);
        }
    }
    __syncthreads();   // before strip reuse as cred
    {
        int* cred = (int*)strip;
        cred[tid] = cnt;
        if (tid < 192) cred[832 + tid] = 0;   // pad to 1024
        __syncthreads();
        for (int off = 512; off > 0; off >>= 1) {
            if (tid < off) cred[tid] += cred[tid + off];
            __syncthreads();
        }
        if (tid == 0) counters[bid] = cred[0];  // per-block partial, no atomics
    }
}

// ---------------------------------------------------------------------------
// NMS diou + compm (proven, verbatim).
// ---------------------------------------------------------------------------
__global__ __launch_bounds__(256) void diou_compm_kernel(
    const unsigned long long* __restrict__ packed, const int* __restrict__ labels,
    float* __restrict__ diouT, float* __restrict__ compm) {
    #pragma clang fp contract(off)
    __shared__ unsigned long long colj[WORDS];
    __shared__ float red[NM];
    const int j = blockIdx.x, i = threadIdx.x;
    colj[i] = packed[i * NM + j];
    __syncthreads();
    int inter = 0, si = 0, sj = 0;
    for (int w = 0; w < WORDS; ++w) {
        unsigned long long a = colj[w];
        unsigned long long b = packed[w * NM + i];
        inter += __popcll(a & b);
        sj += __popcll(a);
        si += __popcll(b);
    }
    float d = 0.0f;
    if (j > i && labels[i] == labels[j]) {
        float u = (float)(si + sj - inter);   // exact integers in f32
        d = (float)inter / u;
    }
    diouT[j * NM + i] = d;
    red[i] = d;
    __syncthreads();
    for (int off = 128; off > 0; off >>= 1) {
        if (i < off) red[i] = fmaxf(red[i], red[i + off]);
        __syncthreads();
    }
    if (i == 0) {
        float m = red[0];
        float t = m * m;
        compm[j] = expf(-2.0f * t);
    }
}

// ---------------------------------------------------------------------------
// coef (proven prologue, verbatim) + valid from per-block partial counts.
// ---------------------------------------------------------------------------
__global__ __launch_bounds__(256) void coef_valid_kernel(
    const float* __restrict__ scores, const float* __restrict__ diouT,
    const float* __restrict__ compm, const int* __restrict__ counters,
    float* __restrict__ out) {
    #pragma clang fp contract(off)
    __shared__ float red[NM];
    const int bid = blockIdx.x, tid = threadIdx.x;
    float d = diouT[bid * NM + tid];
    float dd = d * d;
    float dec = expf(-2.0f * dd);
    red[tid] = dec / compm[tid];
    __syncthreads();
    for (int off = 128; off > 0; off >>= 1) {
        if (tid < off) red[tid] = fminf(red[tid], red[tid + off]);
        __syncthreads();
    }
    if (tid == 0) out[bid] = scores[bid] * red[0];
    if (bid == 0 && tid < NI) {
        int c = counters[4 * tid] + counters[4 * tid + 1] +
                counters[4 * tid + 2] + counters[4 * tid + 3];
        // 16384*0.05 = 819.2, 16384*0.95 = 15564.8; counts are integers
        out[NM + (size_t)NI * HW + tid] = (c >= 820 && c <= 15564) ? 1.0f : 0.0f;
    }
}

extern "C" void kernel_launch(void* const* d_in, const int* in_sizes, int n_in,
                              void* d_out, int out_size, void* d_ws, size_t ws_size,
                              hipStream_t stream) {
    const float* seg = (const float*)d_in[0];
    const float* cate_scores = (const float*)d_in[1];
    const float* feat = (const float*)d_in[2];
    const float* x = (const float*)d_in[3];
    const float* targets = (const float*)d_in[4];
    const int* labels = (const int*)d_in[5];
    float* out = (float*)d_out;
    char* ws = (char*)d_ws;

    unsigned long long* packed = (unsigned long long*)(ws + OFF_PACKED);
    float* diouT = (float*)(ws + OFF_DIOUT);
    float* compm = (float*)(ws + OFF_COMPM);
    int* counters = (int*)(ws + OFF_CNT);

    // Node 1: full 10-iter CRF + pack + masks + per-block counts
    crf10_kernel<<<NBLK, NTHREADS, 0, stream>>>(feat, seg, packed, x, targets,
                                                out, counters);
    // Node 2: NMS diou + compm (needs packed)
    diou_compm_kernel<<<NM, 256, 0, stream>>>(packed, labels, diouT, compm);
    // Node 3: coef + valid (needs diouT/compm/counters)
    coef_valid_kernel<<<NM, 256, 0, stream>>>(cate_scores, diouT, compm,
                                              counters, out);
}